// Round 7
// baseline (1495.127 us; speedup 1.0000x reference)
//
#include <hip/hip_runtime.h>

typedef unsigned int u32;
typedef unsigned short us16;
typedef __bf16 bf16x8 __attribute__((ext_vector_type(8)));
typedef float f32x4 __attribute__((ext_vector_type(4)));

// ---------- constants ----------
constexpr int S    = 2304;   // tokens per stream
constexpr int S2   = 4608;   // both streams
constexpr int D    = 2048;
constexpr int NQKV = 3 * D;  // 6144 — QKV mega-GEMM N (q|k|v)
constexpr int NH   = 16;
constexpr int HD   = 128;
constexpr int FFN  = 8192;
constexpr int CT   = 1152;   // combined tokens per frame (24 * 48)
constexpr float ATTN_SCALE = 0.08838834764831845f; // 128^-0.5

// ---------- helpers ----------
__device__ __forceinline__ us16 f2bf(float f) {
  u32 x = __float_as_uint(f);
  x += 0x7fffu + ((x >> 16) & 1u);   // RNE
  return (us16)(x >> 16);
}
__device__ __forceinline__ float blk_sum256(float v, float* red, int tid) {
  #pragma unroll
  for (int o = 32; o; o >>= 1) v += __shfl_down(v, o, 64);
  __syncthreads();
  if ((tid & 63) == 0) red[tid >> 6] = v;
  __syncthreads();
  return red[0] + red[1] + red[2] + red[3];
}

// async global->LDS, 16B per lane (wave-uniform LDS base + lane*16).
typedef const __attribute__((address_space(1))) void* gas_ptr;
typedef __attribute__((address_space(3))) void* las_ptr;
__device__ __forceinline__ void gload16(const us16* g, us16* l) {
  __builtin_amdgcn_global_load_lds((gas_ptr)g, (las_ptr)l, 16, 0, 0);
}

__device__ __forceinline__ float gelu_tanh(float x) {
  float y = 0.7978845608028654f * (x + 0.044715f * x * x * x);
  float e = __expf(2.0f * y);
  float t = 1.0f - 2.0f / (e + 1.0f);
  return 0.5f * x * (1.0f + t);
}

// ---------- fp32 (KxN) -> bf16 transposed (NxK) ----------
__global__ __launch_bounds__(256) void transpose_cvt(
    const float* __restrict__ in, us16* __restrict__ out, int Kd, int Nd) {
  __shared__ float tile[32][33];
  int tx = threadIdx.x, ty = threadIdx.y;
  int n0 = blockIdx.x * 32, k0 = blockIdx.y * 32;
  #pragma unroll
  for (int i = 0; i < 4; i++)
    tile[ty + i * 8][tx] = in[(size_t)(k0 + ty + i * 8) * Nd + n0 + tx];
  __syncthreads();
  #pragma unroll
  for (int i = 0; i < 4; i++)
    out[(size_t)(n0 + ty + i * 8) * Kd + k0 + tx] = f2bf(tile[tx][ty + i * 8]);
}

// ---------- t = silu(temb) @ lw + lb  (two sets: ln1, ln2) ----------
__global__ __launch_bounds__(256) void temb_mod(
    const float* __restrict__ temb,
    const float* __restrict__ lw1, const float* __restrict__ lb1,
    const float* __restrict__ lw2, const float* __restrict__ lb2,
    float* __restrict__ t1, float* __restrict__ t2) {
  __shared__ float st[512];
  int tid = threadIdx.x;
  for (int i = tid; i < 512; i += 256) {
    float v = temb[i];
    st[i] = v / (1.0f + __expf(-v));
  }
  __syncthreads();
  int which = blockIdx.x / 24;
  int n = (blockIdx.x % 24) * 256 + tid;
  const float* lw = which ? lw2 : lw1;
  const float* lb = which ? lb2 : lb1;
  float acc = lb[n];
  #pragma unroll 4
  for (int k = 0; k < 512; k++) acc += st[k] * lw[(size_t)k * (3 * D) + n];
  (which ? t2 : t1)[n] = acc;
}

// ---------- layernorm + adaLN modulate -> bf16 ----------
__global__ __launch_bounds__(256) void ln_mod(
    const float* __restrict__ x, const float* __restrict__ t,
    const float* __restrict__ nw, const float* __restrict__ nb,
    us16* __restrict__ out) {
  __shared__ float red[4];
  int tok = blockIdx.x, tid = threadIdx.x;
  const float* xr = x + (size_t)tok * D;
  float v[8];
  float4 a = *(const float4*)(xr + tid * 8);
  float4 b = *(const float4*)(xr + tid * 8 + 4);
  v[0]=a.x; v[1]=a.y; v[2]=a.z; v[3]=a.w; v[4]=b.x; v[5]=b.y; v[6]=b.z; v[7]=b.w;
  float s = 0;
  #pragma unroll
  for (int i = 0; i < 8; i++) s += v[i];
  float mu = blk_sum256(s, red, tid) * (1.0f / D);
  float sq = 0;
  #pragma unroll
  for (int i = 0; i < 8; i++) { float d = v[i] - mu; sq += d * d; }
  float var = blk_sum256(sq, red, tid) * (1.0f / D);
  float rinv = rsqrtf(var + 1e-5f);
  int n = tid * 8;
  us16 o[8];
  #pragma unroll
  for (int i = 0; i < 8; i++) {
    float xn = (v[i] - mu) * rinv * nw[n + i] + nb[n + i];
    float y = xn * (1.0f + t[D + n + i]) + t[n + i];
    o[i] = f2bf(y);
  }
  *(uint4*)(out + (size_t)tok * D + n) = *(uint4*)o;
}

// ---------- GEMM 128x128 (R4-measured structure), 256 thr ----------
// C(MxN) = A(MxK,bf16) @ BT(NxK,bf16)^T + bias
// EPI 0: fp32 C   EPI 1: bf16 gelu(C)
// EPI 2: fp32 C = x + gate[col]*(acc+bias)   (fused residual: WO, FFN2)
template <int EPI>
__global__ __launch_bounds__(256) void gemm128(
    const us16* __restrict__ A, const us16* __restrict__ BT,
    const float* __restrict__ b0, const float* __restrict__ b1,
    const float* __restrict__ b2, int bmask, void* __restrict__ Cout,
    int M, int N, int K,
    const float* __restrict__ xa, const float* __restrict__ xb,
    const float* __restrict__ gate) {
  __shared__ __align__(16) us16 As[128 * 32];
  __shared__ __align__(16) us16 Bs[128 * 32];
  const int tid = threadIdx.x;

  const int nbx = N >> 7;
  const int nwg = nbx * (M >> 7);
  int bid = (int)blockIdx.x;
  bid = (bid & 7) * (nwg >> 3) + (bid >> 3);   // XCD-contiguous chunks (nwg%8==0)
  const int by = bid / nbx;
  const int m0 = by << 7;
  const int n0 = (bid - by * nbx) << 7;

  const int srow = tid >> 2;            // 0..63
  const int scol = (tid & 3) << 3;      // 0,8,16,24
  const us16* Ap = A + (size_t)(m0 + srow) * K + scol;
  const us16* Bp = BT + (size_t)(n0 + srow) * K + scol;
  const size_t rstep = (size_t)64 * K;
  us16* lA = As + ((tid >> 6) << 9);    // wave-uniform base; HW adds lane*16B
  us16* lB = Bs + ((tid >> 6) << 9);

  const int w = tid >> 6, l = tid & 63;
  const int wr = (w >> 1) << 6, wc = (w & 1) << 6;
  const int m = l & 15, quad = l >> 4;
  const us16* Ard = As + (wr + m) * 32 + quad * 8;
  const us16* Brd = Bs + (wc + m) * 32 + quad * 8;

  f32x4 acc[4][4] = {};
  for (int k0 = 0; k0 < K; k0 += 32) {
    __syncthreads();                    // prev iter's ds_reads done
    gload16(Ap + k0, lA);
    gload16(Ap + rstep + k0, lA + 2048);
    gload16(Bp + k0, lB);
    gload16(Bp + rstep + k0, lB + 2048);
    __syncthreads();                    // drains vmcnt: tile resident
    bf16x8 af[4], bf[4];
    #pragma unroll
    for (int i = 0; i < 4; i++) {
      af[i] = *(const bf16x8*)(Ard + i * 512);
      bf[i] = *(const bf16x8*)(Brd + i * 512);
    }
    #pragma unroll
    for (int mi = 0; mi < 4; mi++)
      #pragma unroll
      for (int ni = 0; ni < 4; ni++)
        acc[mi][ni] = __builtin_amdgcn_mfma_f32_16x16x32_bf16(
            af[mi], bf[ni], acc[mi][ni], 0, 0, 0);
  }

  const float* bp = b0;
  if (b1) { int seg = (n0 + wc) >> 11; if (seg == 1) bp = b1; else if (seg >= 2) bp = b2; }

  const int r0 = m0 + wr + (quad << 2);
  #pragma unroll
  for (int ni = 0; ni < 4; ni++) {
    const int col = n0 + wc + ni * 16 + m;
    const float bv = bp ? bp[col & bmask] : 0.0f;
    #pragma unroll
    for (int mi = 0; mi < 4; mi++) {
      const int row = r0 + mi * 16;
      #pragma unroll
      for (int r = 0; r < 4; r++) {
        float y = acc[mi][ni][r] + bv;
        if constexpr (EPI == 1) {
          ((us16*)Cout)[(size_t)(row + r) * N + col] = f2bf(gelu_tanh(y));
        } else if constexpr (EPI == 2) {
          const int rr = row + r;
          const float xv = (rr < S) ? xa[(size_t)rr * N + col]
                                    : xb[(size_t)(rr - S) * N + col];
          ((float*)Cout)[(size_t)rr * N + col] = xv + gate[col & bmask] * y;
        } else {
          ((float*)Cout)[(size_t)(row + r) * N + col] = y;
        }
      }
    }
  }
}

// ---------- GEMM 128x256 (same R4 loop structure), 512 thr, 8 waves ----
// Better reuse: staged bytes/FLOP = (128+256)/(128*256) vs 256/(128*128)
// (-25%). Wave grid 2(M)x4(N); per-wave code identical to gemm128.
// Per iter per wave: 1 A-gload + 2 B-gloads; LDS 24KB.
template <int EPI>
__global__ __launch_bounds__(512) void gemmW(
    const us16* __restrict__ A, const us16* __restrict__ BT,
    const float* __restrict__ b0, const float* __restrict__ b1,
    const float* __restrict__ b2, int bmask, void* __restrict__ Cout,
    int M, int N, int K) {
  __shared__ __align__(16) us16 As[128 * 32];   // 8KB
  __shared__ __align__(16) us16 Bs[256 * 32];   // 16KB
  const int tid = threadIdx.x;

  const int nbx = N >> 8;
  const int nwg = nbx * (M >> 7);
  int bid = (int)blockIdx.x;
  bid = (bid & 7) * (nwg >> 3) + (bid >> 3);   // XCD-contiguous (nwg%8==0)
  const int by = bid / nbx;
  const int m0 = by << 7;
  const int n0 = (bid - by * nbx) << 8;

  const int srow = tid >> 2;            // 0..127
  const int scol = (tid & 3) << 3;
  const us16* Ap  = A  + (size_t)(m0 + srow) * K + scol;
  const us16* Bp  = BT + (size_t)(n0 + srow) * K + scol;        // rows 0..127
  const us16* Bp2 = BT + (size_t)(n0 + 128 + srow) * K + scol;  // rows 128..255
  const int w = tid >> 6;
  us16* lA = As + (w << 9);             // wave-uniform; HW adds lane*16B
  us16* lB = Bs + (w << 9);

  const int l = tid & 63;
  const int wr = (w >> 2) << 6;         // 0,64
  const int wc = (w & 3) << 6;          // 0,64,128,192
  const int m = l & 15, quad = l >> 4;
  const us16* Ard = As + (wr + m) * 32 + quad * 8;
  const us16* Brd = Bs + (wc + m) * 32 + quad * 8;

  f32x4 acc[4][4] = {};
  for (int k0 = 0; k0 < K; k0 += 32) {
    __syncthreads();
    gload16(Ap + k0,  lA);
    gload16(Bp + k0,  lB);
    gload16(Bp2 + k0, lB + 4096);
    __syncthreads();
    bf16x8 af[4], bf[4];
    #pragma unroll
    for (int i = 0; i < 4; i++) {
      af[i] = *(const bf16x8*)(Ard + i * 512);
      bf[i] = *(const bf16x8*)(Brd + i * 512);
    }
    #pragma unroll
    for (int mi = 0; mi < 4; mi++)
      #pragma unroll
      for (int ni = 0; ni < 4; ni++)
        acc[mi][ni] = __builtin_amdgcn_mfma_f32_16x16x32_bf16(
            af[mi], bf[ni], acc[mi][ni], 0, 0, 0);
  }

  const float* bp = b0;
  if (b1) { int seg = (n0 + wc) >> 11; if (seg == 1) bp = b1; else if (seg >= 2) bp = b2; }

  const int r0 = m0 + wr + (quad << 2);
  #pragma unroll
  for (int ni = 0; ni < 4; ni++) {
    const int col = n0 + wc + ni * 16 + m;
    const float bv = bp ? bp[col & bmask] : 0.0f;
    #pragma unroll
    for (int mi = 0; mi < 4; mi++) {
      const int row = r0 + mi * 16;
      #pragma unroll
      for (int r = 0; r < 4; r++) {
        float y = acc[mi][ni][r] + bv;
        if constexpr (EPI == 1) {
          ((us16*)Cout)[(size_t)(row + r) * N + col] = f2bf(gelu_tanh(y));
        } else {
          ((float*)Cout)[(size_t)(row + r) * N + col] = y;
        }
      }
    }
  }
}

// ---------- QK rmsnorm + rope + combine-scatter (merged q,k,v) ----------
// raw: [4608][6144] fp32; grid 3*S2 blocks; mode = bid / S2 (0=q,1=k,2=v)
__global__ __launch_bounds__(256) void qkv_scatter(
    const float* __restrict__ raw,
    const float* __restrict__ nq_w, const float* __restrict__ nk_w,
    const float* __restrict__ cos_h, const float* __restrict__ sin_h,
    const float* __restrict__ cos_r, const float* __restrict__ sin_r,
    us16* __restrict__ qc, us16* __restrict__ kc, us16* __restrict__ vc) {
  __shared__ float red[4];
  int bid = blockIdx.x, tid = threadIdx.x;
  int mode = bid / S2;
  int t = bid - mode * S2;
  us16* out = mode == 0 ? qc : (mode == 1 ? kc : vc);
  const float* nw = mode == 1 ? nk_w : nq_w;
  int is_ref = t >= S;
  int tt = is_ref ? t - S : t;
  const float* xr = raw + (size_t)t * NQKV + mode * D;
  float v[8];
  float4 a = *(const float4*)(xr + tid * 8);
  float4 b = *(const float4*)(xr + tid * 8 + 4);
  v[0]=a.x; v[1]=a.y; v[2]=a.z; v[3]=a.w; v[4]=b.x; v[5]=b.y; v[6]=b.z; v[7]=b.w;
  int n = tid * 8;
  int head = n >> 7, d = n & 127;
  float o8[8];
  if (mode < 2) {
    float s = 0;
    #pragma unroll
    for (int i = 0; i < 8; i++) s += v[i] * v[i];
    float tot = blk_sum256(s, red, tid);
    float rinv = rsqrtf(tot * (1.0f / D) + 1e-6f);
    const float* cr = (is_ref ? cos_r : cos_h) + (size_t)tt * HD;
    const float* sr = (is_ref ? sin_r : sin_h) + (size_t)tt * HD;
    #pragma unroll
    for (int p = 0; p < 4; p++) {
      float x1 = v[2 * p] * rinv * nw[n + 2 * p];
      float x2 = v[2 * p + 1] * rinv * nw[n + 2 * p + 1];
      float ce = cr[d + 2 * p];
      float so = sr[d + 2 * p + 1];
      o8[2 * p]     = x1 * ce - x2 * so;
      o8[2 * p + 1] = x1 * so + x2 * ce;
    }
    if (mode == 0) {
      #pragma unroll
      for (int i = 0; i < 8; i++) o8[i] *= ATTN_SCALE;
    }
  } else {
    #pragma unroll
    for (int i = 0; i < 8; i++) o8[i] = v[i];
  }
  int f = tt / 576, rem = tt % 576;
  int row = rem / 24, col = rem - row * 24;
  int comb = row * 48 + col + (is_ref ? 24 : 0);
  size_t oidx = ((size_t)(f * NH + head) * CT + comb) * HD + d;
  us16 packed[8];
  #pragma unroll
  for (int i = 0; i < 8; i++) packed[i] = f2bf(o8[i]);
  *(uint4*)(out + oidx) = *(uint4*)packed;
}

// ---------- MFMA flash attention ----------
// grid: 64 fh * 18 q-tiles; block 256 (4 waves x 16 queries)
__global__ __launch_bounds__(256) void attn_mfma(
    const us16* __restrict__ qc, const us16* __restrict__ kc,
    const us16* __restrict__ vc, us16* __restrict__ ah, us16* __restrict__ ar) {
  __shared__ __align__(16) us16 Qs[64][136];     // stride 272B: frag-read 2-way banks
  __shared__ __align__(16) us16 Ks[64][136];
  __shared__ __align__(16) us16 Vts[128][72];    // transposed V: [d][key]
  __shared__ __align__(16) us16 Ps[4][16][72];   // per-wave P round-trip (C->A layout)
  int tid = threadIdx.x;
  int w = tid >> 6, l = tid & 63;
  int m = l & 15, quad = l >> 4;
  int bx = blockIdx.x;
  int fh = bx / 18, qt = bx % 18;
  size_t base = (size_t)fh * CT * HD;
  int qbase = qt * 64;

  // stage Q tile (64 x 128)
  {
    int row = tid >> 2, c0 = (tid & 3) * 32;
    const us16* src = qc + base + (size_t)(qbase + row) * HD + c0;
    #pragma unroll
    for (int j = 0; j < 4; j++)
      *(uint4*)&Qs[row][c0 + 8 * j] = *(const uint4*)(src + 8 * j);
  }
  __syncthreads();
  bf16x8 qf[4];
  #pragma unroll
  for (int c = 0; c < 4; c++)
    qf[c] = *(const bf16x8*)&Qs[16 * w + m][32 * c + quad * 8];

  float mo[4] = {-1e30f, -1e30f, -1e30f, -1e30f};
  float li[4] = {0.f, 0.f, 0.f, 0.f};
  f32x4 o[8] = {};

  #pragma unroll 1
  for (int kb = 0; kb < CT; kb += 64) {
    __syncthreads();
    {
      int row = tid >> 2, c0 = (tid & 3) * 32;
      const us16* src = kc + base + (size_t)(kb + row) * HD + c0;
      #pragma unroll
      for (int j = 0; j < 4; j++)
        *(uint4*)&Ks[row][c0 + 8 * j] = *(const uint4*)(src + 8 * j);
    }
    {
      int key = tid & 63, d0 = (tid >> 6) * 32;
      const us16* src = vc + base + (size_t)(kb + key) * HD + d0;
      #pragma unroll
      for (int j = 0; j < 4; j++) {
        uint4 vv = *(const uint4*)(src + 8 * j);
        us16 tmp[8];
        *(uint4*)tmp = vv;
        #pragma unroll
        for (int i = 0; i < 8; i++) Vts[d0 + 8 * j + i][key] = tmp[i];
      }
    }
    __syncthreads();
    f32x4 s[4] = {};
    #pragma unroll
    for (int kt = 0; kt < 4; kt++) {
      #pragma unroll
      for (int c = 0; c < 4; c++) {
        bf16x8 kf = *(const bf16x8*)&Ks[kt * 16 + m][32 * c + quad * 8];
        s[kt] = __builtin_amdgcn_mfma_f32_16x16x32_bf16(qf[c], kf, s[kt], 0, 0, 0);
      }
    }
    float al[4];
    #pragma unroll
    for (int r = 0; r < 4; r++) {
      float v = fmaxf(fmaxf(s[0][r], s[1][r]), fmaxf(s[2][r], s[3][r]));
      #pragma unroll
      for (int off = 8; off; off >>= 1) v = fmaxf(v, __shfl_xor(v, off));
      float mn = fmaxf(mo[r], v);
      al[r] = __expf(mo[r] - mn);
      mo[r] = mn;
      float ps = 0.f;
      #pragma unroll
      for (int kt = 0; kt < 4; kt++) {
        float p = __expf(s[kt][r] - mn);
        s[kt][r] = p;
        ps += p;
      }
      #pragma unroll
      for (int off = 8; off; off >>= 1) ps += __shfl_xor(ps, off);
      li[r] = li[r] * al[r] + ps;
    }
    #pragma unroll
    for (int kt = 0; kt < 4; kt++)
      #pragma unroll
      for (int r = 0; r < 4; r++)
        Ps[w][quad * 4 + r][kt * 16 + m] = f2bf(s[kt][r]);
    #pragma unroll
    for (int dt = 0; dt < 8; dt++)
      #pragma unroll
      for (int r = 0; r < 4; r++)
        o[dt][r] *= al[r];
    // barrier: Ps round-trip is cross-lane via LDS; s_barrier's lgkmcnt(0)
    // drain orders the us16 stores vs bf16x8 loads (TBAA won't).
    __syncthreads();
    #pragma unroll
    for (int c = 0; c < 2; c++) {
      bf16x8 pf = *(const bf16x8*)&Ps[w][m][32 * c + quad * 8];
      #pragma unroll
      for (int dt = 0; dt < 8; dt++) {
        bf16x8 vf = *(const bf16x8*)&Vts[dt * 16 + m][32 * c + quad * 8];
        o[dt] = __builtin_amdgcn_mfma_f32_16x16x32_bf16(pf, vf, o[dt], 0, 0, 0);
      }
    }
  }
  int f = fh >> 4, h = fh & 15;
  #pragma unroll
  for (int r = 0; r < 4; r++) {
    float rl = 1.0f / li[r];
    int q = qbase + 16 * w + quad * 4 + r;
    int row = q / 48, cc = q - row * 48;
    int isr = cc >= 24;
    int tok = f * 576 + row * 24 + (isr ? cc - 24 : cc);
    us16* dstp = (isr ? ar : ah) + (size_t)tok * D + h * HD;
    #pragma unroll
    for (int dt = 0; dt < 8; dt++)
      dstp[dt * 16 + m] = f2bf(o[dt][r] * rl);
  }
}

// ---------- workspace layout (bytes) ----------
constexpr size_t O_WQ   = 0;          // bf16 DxD; wq|wk|wv contiguous = QKV BT
constexpr size_t O_WK   = 8388608;
constexpr size_t O_WV   = 16777216;
constexpr size_t O_WO   = 25165824;   // bf16 DxD
constexpr size_t O_NHR  = 33603584;   // bf16 [4608][2048] (h||r), ends 52477952
constexpr size_t O_RAW  = 52477952;   // fp32 [4608][6144] = 113.2MB, ends 165724160
constexpr size_t O_QC   = 165724160;  // bf16 combined per-head
constexpr size_t O_KC   = 184598528;
constexpr size_t O_VC   = 203472896;  // ends 222347264
constexpr size_t O_T1   = 222347264;  // fp32 6144
constexpr size_t O_T2   = 222371840;  // fp32 6144, ends 222396416
constexpr size_t O_AH   = O_RAW;      // bf16 [4608][2048] (ah||ar)
// Phase B (FFN) — overlays dead phase-A regions (stream-ordered):
constexpr size_t O_W1T  = 0;          // bf16 FFN*D = 33.5MB (over wq/wk/wv/wo)
constexpr size_t O_W2T  = 33554432;   // bf16 D*FFN (over nhr + dead raw/ah; after WO)
constexpr size_t O_N2   = 67108864;   // bf16 [4608][2048], ends 85983232
constexpr size_t O_MIDB = 85983232;   // bf16 [4608][8192] = 75.5MB, ends 161480704

extern "C" void kernel_launch(void* const* d_in, const int* in_sizes, int n_in,
                              void* d_out, int out_size, void* d_ws, size_t ws_size,
                              hipStream_t stream) {
  (void)in_sizes; (void)n_in; (void)out_size; (void)ws_size;
  const float* hidden = (const float*)d_in[0];
  const float* refs   = (const float*)d_in[1];
  const float* temb   = (const float*)d_in[2];
  const float* cos_h  = (const float*)d_in[3];
  const float* sin_h  = (const float*)d_in[4];
  const float* cos_r  = (const float*)d_in[5];
  const float* sin_r  = (const float*)d_in[6];
  const float* ln1_lw = (const float*)d_in[7];
  const float* ln1_lb = (const float*)d_in[8];
  const float* ln1_nw = (const float*)d_in[9];
  const float* ln1_nb = (const float*)d_in[10];
  const float* ln2_lw = (const float*)d_in[11];
  const float* ln2_lb = (const float*)d_in[12];
  const float* ln2_nw = (const float*)d_in[13];
  const float* ln2_nb = (const float*)d_in[14];
  const float* wq = (const float*)d_in[15];
  const float* bq = (const float*)d_in[16];
  const float* wk = (const float*)d_in[17];
  const float* bk = (const float*)d_in[18];
  const float* wv = (const float*)d_in[19];
  const float* bv = (const float*)d_in[20];
  const float* nq_w = (const float*)d_in[21];
  const float* nk_w = (const float*)d_in[22];
  const float* wo = (const float*)d_in[23];
  const float* bo = (const float*)d_in[24];
  const float* ffn_w1 = (const float*)d_in[25];
  const float* ffn_b1 = (const float*)d_in[26];
  const float* ffn_w2 = (const float*)d_in[27];
  const float* ffn_b2 = (const float*)d_in[28];

  char* ws = (char*)d_ws;
  us16* p_wq  = (us16*)(ws + O_WQ);
  us16* p_wk  = (us16*)(ws + O_WK);
  us16* p_wv  = (us16*)(ws + O_WV);
  us16* p_wo  = (us16*)(ws + O_WO);
  us16* p_nhr = (us16*)(ws + O_NHR);
  float* p_raw = (float*)(ws + O_RAW);
  us16* p_qc  = (us16*)(ws + O_QC);
  us16* p_kc  = (us16*)(ws + O_KC);
  us16* p_vc  = (us16*)(ws + O_VC);
  float* p_t1 = (float*)(ws + O_T1);
  float* p_t2 = (float*)(ws + O_T2);
  us16* p_ah  = (us16*)(ws + O_AH);                 // h half
  us16* p_ar  = p_ah + (size_t)S * D;               // r half (contiguous)
  us16* p_w1t = (us16*)(ws + O_W1T);
  us16* p_w2t = (us16*)(ws + O_W2T);
  us16* p_n2  = (us16*)(ws + O_N2);
  us16* p_midb = (us16*)(ws + O_MIDB);
  float* outd = (float*)d_out;                      // [4608][2048] (h||r)

  // grids (all %8==0 for the bijective XCD swizzle)
  constexpr int G_QKV  = (NQKV / 256) * (S2 / 128);    // 24*36 = 864
  constexpr int G_WO   = (D / 128) * (S2 / 128);       // 16*36 = 576
  constexpr int G_FFN1 = (FFN / 256) * (S2 / 128);     // 32*36 = 1152
  constexpr int G_FFN2 = G_WO;                         // 576

  dim3 tb(32, 8);
  // --- phase A: attention ---
  transpose_cvt<<<dim3(64, 64), tb, 0, stream>>>(wq, p_wq, D, D);
  transpose_cvt<<<dim3(64, 64), tb, 0, stream>>>(wk, p_wk, D, D);
  transpose_cvt<<<dim3(64, 64), tb, 0, stream>>>(wv, p_wv, D, D);
  transpose_cvt<<<dim3(64, 64), tb, 0, stream>>>(wo, p_wo, D, D);
  temb_mod<<<48, 256, 0, stream>>>(temb, ln1_lw, ln1_lb, ln2_lw, ln2_lb, p_t1, p_t2);
  ln_mod<<<S, 256, 0, stream>>>(hidden, p_t1, ln1_nw, ln1_nb, p_nhr);
  ln_mod<<<S, 256, 0, stream>>>(refs,   p_t1, ln1_nw, ln1_nb, p_nhr + (size_t)S * D);
  // QKV mega-GEMM: [4608 x 6144] = nhr @ [wq|wk|wv]^T  (128x256 tiles)
  gemmW<0><<<G_QKV, 512, 0, stream>>>(p_nhr, p_wq, bq, bk, bv, D - 1,
                                      p_raw, S2, NQKV, D);
  qkv_scatter<<<3 * S2, 256, 0, stream>>>(p_raw, nq_w, nk_w,
                                          cos_h, sin_h, cos_r, sin_r,
                                          p_qc, p_kc, p_vc);
  attn_mfma<<<64 * 18, 256, 0, stream>>>(p_qc, p_kc, p_vc, p_ah, p_ar);
  // WO + fused residual: d_out = x + gate1*(attn @ wo + bo)
  gemm128<2><<<G_WO, 256, 0, stream>>>(p_ah, p_wo, bo, nullptr, nullptr, D - 1,
                                       outd, S2, D, D,
                                       hidden, refs, p_t1 + 2 * D);
  // --- phase B: FFN (both streams batched) ---
  transpose_cvt<<<dim3(256, 64), tb, 0, stream>>>(ffn_w1, p_w1t, D, FFN);
  transpose_cvt<<<dim3(64, 256), tb, 0, stream>>>(ffn_w2, p_w2t, FFN, D);
  ln_mod<<<S2, 256, 0, stream>>>(outd, p_t2, ln2_nw, ln2_nb, p_n2);
  // FFN1 (gelu fused -> bf16), 128x256 tiles
  gemmW<1><<<G_FFN1, 512, 0, stream>>>(p_n2, p_w1t, ffn_b1, nullptr, nullptr,
                                       FFN - 1, p_midb, S2, FFN, D);
  // FFN2 + fused residual: d_out = d_out + gate2*(midb @ w2 + b2)
  gemm128<2><<<G_FFN2, 256, 0, stream>>>(p_midb, p_w2t, ffn_b2, nullptr, nullptr,
                                         D - 1, outd, S2, D, FFN,
                                         outd, outd + (size_t)S * D, p_t2 + 2 * D);
}

// Round 8
// 1292.548 us; speedup vs baseline: 1.1567x; 1.1567x over previous
//
#include <hip/hip_runtime.h>

typedef unsigned int u32;
typedef unsigned short us16;
typedef __bf16 bf16x8 __attribute__((ext_vector_type(8)));
typedef float f32x4 __attribute__((ext_vector_type(4)));

// ---------- constants ----------
constexpr int S    = 2304;   // tokens per stream
constexpr int S2   = 4608;   // both streams
constexpr int D    = 2048;
constexpr int NQKV = 3 * D;  // 6144 — QKV mega-GEMM N (q|k|v)
constexpr int NH   = 16;
constexpr int HD   = 128;
constexpr int FFN  = 8192;
constexpr int CT   = 1152;   // combined tokens per frame (24 * 48)
constexpr float ATTN_SCALE = 0.08838834764831845f; // 128^-0.5

// ---------- helpers ----------
__device__ __forceinline__ us16 f2bf(float f) {
  u32 x = __float_as_uint(f);
  x += 0x7fffu + ((x >> 16) & 1u);   // RNE
  return (us16)(x >> 16);
}
__device__ __forceinline__ float blk_sum256(float v, float* red, int tid) {
  #pragma unroll
  for (int o = 32; o; o >>= 1) v += __shfl_down(v, o, 64);
  __syncthreads();
  if ((tid & 63) == 0) red[tid >> 6] = v;
  __syncthreads();
  return red[0] + red[1] + red[2] + red[3];
}

// async global->LDS, 16B per lane (wave-uniform LDS base + lane*16).
typedef const __attribute__((address_space(1))) void* gas_ptr;
typedef __attribute__((address_space(3))) void* las_ptr;
__device__ __forceinline__ void gload16(const us16* g, us16* l) {
  __builtin_amdgcn_global_load_lds((gas_ptr)g, (las_ptr)l, 16, 0, 0);
}

__device__ __forceinline__ float gelu_tanh(float x) {
  float y = 0.7978845608028654f * (x + 0.044715f * x * x * x);
  float e = __expf(2.0f * y);
  float t = 1.0f - 2.0f / (e + 1.0f);
  return 0.5f * x * (1.0f + t);
}

// ---------- fp32 (KxN) -> bf16 transposed (NxK) ----------
__global__ __launch_bounds__(256) void transpose_cvt(
    const float* __restrict__ in, us16* __restrict__ out, int Kd, int Nd) {
  __shared__ float tile[32][33];
  int tx = threadIdx.x, ty = threadIdx.y;
  int n0 = blockIdx.x * 32, k0 = blockIdx.y * 32;
  #pragma unroll
  for (int i = 0; i < 4; i++)
    tile[ty + i * 8][tx] = in[(size_t)(k0 + ty + i * 8) * Nd + n0 + tx];
  __syncthreads();
  #pragma unroll
  for (int i = 0; i < 4; i++)
    out[(size_t)(n0 + ty + i * 8) * Kd + k0 + tx] = f2bf(tile[tx][ty + i * 8]);
}

// ---------- t = silu(temb) @ lw + lb  (two sets: ln1, ln2) ----------
__global__ __launch_bounds__(256) void temb_mod(
    const float* __restrict__ temb,
    const float* __restrict__ lw1, const float* __restrict__ lb1,
    const float* __restrict__ lw2, const float* __restrict__ lb2,
    float* __restrict__ t1, float* __restrict__ t2) {
  __shared__ float st[512];
  int tid = threadIdx.x;
  for (int i = tid; i < 512; i += 256) {
    float v = temb[i];
    st[i] = v / (1.0f + __expf(-v));
  }
  __syncthreads();
  int which = blockIdx.x / 24;
  int n = (blockIdx.x % 24) * 256 + tid;
  const float* lw = which ? lw2 : lw1;
  const float* lb = which ? lb2 : lb1;
  float acc = lb[n];
  #pragma unroll 4
  for (int k = 0; k < 512; k++) acc += st[k] * lw[(size_t)k * (3 * D) + n];
  (which ? t2 : t1)[n] = acc;
}

// ---------- layernorm + adaLN modulate -> bf16 ----------
__global__ __launch_bounds__(256) void ln_mod(
    const float* __restrict__ x, const float* __restrict__ t,
    const float* __restrict__ nw, const float* __restrict__ nb,
    us16* __restrict__ out) {
  __shared__ float red[4];
  int tok = blockIdx.x, tid = threadIdx.x;
  const float* xr = x + (size_t)tok * D;
  float v[8];
  float4 a = *(const float4*)(xr + tid * 8);
  float4 b = *(const float4*)(xr + tid * 8 + 4);
  v[0]=a.x; v[1]=a.y; v[2]=a.z; v[3]=a.w; v[4]=b.x; v[5]=b.y; v[6]=b.z; v[7]=b.w;
  float s = 0;
  #pragma unroll
  for (int i = 0; i < 8; i++) s += v[i];
  float mu = blk_sum256(s, red, tid) * (1.0f / D);
  float sq = 0;
  #pragma unroll
  for (int i = 0; i < 8; i++) { float d = v[i] - mu; sq += d * d; }
  float var = blk_sum256(sq, red, tid) * (1.0f / D);
  float rinv = rsqrtf(var + 1e-5f);
  int n = tid * 8;
  us16 o[8];
  #pragma unroll
  for (int i = 0; i < 8; i++) {
    float xn = (v[i] - mu) * rinv * nw[n + i] + nb[n + i];
    float y = xn * (1.0f + t[D + n + i]) + t[n + i];
    o[i] = f2bf(y);
  }
  *(uint4*)(out + (size_t)tok * D + n) = *(uint4*)o;
}

// ---------- GEMM 128x128 (R4-measured structure), 256 thr ----------
// C(MxN,f32) = A(MxK,bf16) @ BT(NxK,bf16)^T + bias
__global__ __launch_bounds__(256) void gemm128(
    const us16* __restrict__ A, const us16* __restrict__ BT,
    const float* __restrict__ b0, float* __restrict__ Cout,
    int M, int N, int K) {
  __shared__ __align__(16) us16 As[128 * 32];
  __shared__ __align__(16) us16 Bs[128 * 32];
  const int tid = threadIdx.x;

  const int nbx = N >> 7;
  const int nwg = nbx * (M >> 7);
  int bid = (int)blockIdx.x;
  bid = (bid & 7) * (nwg >> 3) + (bid >> 3);   // XCD-contiguous chunks (nwg%8==0)
  const int by = bid / nbx;
  const int m0 = by << 7;
  const int n0 = (bid - by * nbx) << 7;

  const int srow = tid >> 2;            // 0..63
  const int scol = (tid & 3) << 3;      // 0,8,16,24
  const us16* Ap = A + (size_t)(m0 + srow) * K + scol;
  const us16* Bp = BT + (size_t)(n0 + srow) * K + scol;
  const size_t rstep = (size_t)64 * K;
  us16* lA = As + ((tid >> 6) << 9);    // wave-uniform base; HW adds lane*16B
  us16* lB = Bs + ((tid >> 6) << 9);

  const int w = tid >> 6, l = tid & 63;
  const int wr = (w >> 1) << 6, wc = (w & 1) << 6;
  const int m = l & 15, quad = l >> 4;
  const us16* Ard = As + (wr + m) * 32 + quad * 8;
  const us16* Brd = Bs + (wc + m) * 32 + quad * 8;

  f32x4 acc[4][4] = {};
  for (int k0 = 0; k0 < K; k0 += 32) {
    __syncthreads();                    // prev iter's ds_reads done
    gload16(Ap + k0, lA);
    gload16(Ap + rstep + k0, lA + 2048);
    gload16(Bp + k0, lB);
    gload16(Bp + rstep + k0, lB + 2048);
    __syncthreads();                    // drains vmcnt: tile resident
    bf16x8 af[4], bf[4];
    #pragma unroll
    for (int i = 0; i < 4; i++) {
      af[i] = *(const bf16x8*)(Ard + i * 512);
      bf[i] = *(const bf16x8*)(Brd + i * 512);
    }
    #pragma unroll
    for (int mi = 0; mi < 4; mi++)
      #pragma unroll
      for (int ni = 0; ni < 4; ni++)
        acc[mi][ni] = __builtin_amdgcn_mfma_f32_16x16x32_bf16(
            af[mi], bf[ni], acc[mi][ni], 0, 0, 0);
  }

  const int r0 = m0 + wr + (quad << 2);
  #pragma unroll
  for (int ni = 0; ni < 4; ni++) {
    const int col = n0 + wc + ni * 16 + m;
    const float bv = b0[col];
    #pragma unroll
    for (int mi = 0; mi < 4; mi++) {
      const int row = r0 + mi * 16;
      #pragma unroll
      for (int r = 0; r < 4; r++)
        Cout[(size_t)(row + r) * N + col] = acc[mi][ni][r] + bv;
    }
  }
}

// ---------- GEMM 128x256 (same loop structure), 512 thr, 8 waves ----
// Reuse: staged bytes/FLOP (128+256)/(128*256) vs 256/128^2 (-25%).
// EPI 0: fp32 C (+ per-2048-segment bias select for QKV)   EPI 1: bf16 gelu(C)
template <int EPI>
__global__ __launch_bounds__(512) void gemmW(
    const us16* __restrict__ A, const us16* __restrict__ BT,
    const float* __restrict__ b0, const float* __restrict__ b1,
    const float* __restrict__ b2, int bmask, void* __restrict__ Cout,
    int M, int N, int K) {
  __shared__ __align__(16) us16 As[128 * 32];   // 8KB
  __shared__ __align__(16) us16 Bs[256 * 32];   // 16KB
  const int tid = threadIdx.x;

  const int nbx = N >> 8;
  const int nwg = nbx * (M >> 7);
  int bid = (int)blockIdx.x;
  bid = (bid & 7) * (nwg >> 3) + (bid >> 3);   // XCD-contiguous (nwg%8==0)
  const int by = bid / nbx;
  const int m0 = by << 7;
  const int n0 = (bid - by * nbx) << 8;

  const int srow = tid >> 2;            // 0..127
  const int scol = (tid & 3) << 3;
  const us16* Ap  = A  + (size_t)(m0 + srow) * K + scol;
  const us16* Bp  = BT + (size_t)(n0 + srow) * K + scol;        // rows 0..127
  const us16* Bp2 = BT + (size_t)(n0 + 128 + srow) * K + scol;  // rows 128..255
  const int w = tid >> 6;
  us16* lA = As + (w << 9);             // wave-uniform; HW adds lane*16B
  us16* lB = Bs + (w << 9);

  const int l = tid & 63;
  const int wr = (w >> 2) << 6;         // 0,64
  const int wc = (w & 3) << 6;          // 0,64,128,192
  const int m = l & 15, quad = l >> 4;
  const us16* Ard = As + (wr + m) * 32 + quad * 8;
  const us16* Brd = Bs + (wc + m) * 32 + quad * 8;

  f32x4 acc[4][4] = {};
  for (int k0 = 0; k0 < K; k0 += 32) {
    __syncthreads();
    gload16(Ap + k0,  lA);
    gload16(Bp + k0,  lB);
    gload16(Bp2 + k0, lB + 4096);
    __syncthreads();
    bf16x8 af[4], bf[4];
    #pragma unroll
    for (int i = 0; i < 4; i++) {
      af[i] = *(const bf16x8*)(Ard + i * 512);
      bf[i] = *(const bf16x8*)(Brd + i * 512);
    }
    #pragma unroll
    for (int mi = 0; mi < 4; mi++)
      #pragma unroll
      for (int ni = 0; ni < 4; ni++)
        acc[mi][ni] = __builtin_amdgcn_mfma_f32_16x16x32_bf16(
            af[mi], bf[ni], acc[mi][ni], 0, 0, 0);
  }

  const float* bp = b0;
  if (b1) { int seg = (n0 + wc) >> 11; if (seg == 1) bp = b1; else if (seg >= 2) bp = b2; }

  const int r0 = m0 + wr + (quad << 2);
  #pragma unroll
  for (int ni = 0; ni < 4; ni++) {
    const int col = n0 + wc + ni * 16 + m;
    const float bv = bp[col & bmask];
    #pragma unroll
    for (int mi = 0; mi < 4; mi++) {
      const int row = r0 + mi * 16;
      #pragma unroll
      for (int r = 0; r < 4; r++) {
        float y = acc[mi][ni][r] + bv;
        if constexpr (EPI == 1) {
          ((us16*)Cout)[(size_t)(row + r) * N + col] = f2bf(gelu_tanh(y));
        } else {
          ((float*)Cout)[(size_t)(row + r) * N + col] = y;
        }
      }
    }
  }
}

// ---------- QK rmsnorm + rope + combine-scatter (merged q,k,v) ----------
// raw: [4608][6144] fp32; grid 3*S2 blocks; mode = bid / S2 (0=q,1=k,2=v)
__global__ __launch_bounds__(256) void qkv_scatter(
    const float* __restrict__ raw,
    const float* __restrict__ nq_w, const float* __restrict__ nk_w,
    const float* __restrict__ cos_h, const float* __restrict__ sin_h,
    const float* __restrict__ cos_r, const float* __restrict__ sin_r,
    us16* __restrict__ qc, us16* __restrict__ kc, us16* __restrict__ vc) {
  __shared__ float red[4];
  int bid = blockIdx.x, tid = threadIdx.x;
  int mode = bid / S2;
  int t = bid - mode * S2;
  us16* out = mode == 0 ? qc : (mode == 1 ? kc : vc);
  const float* nw = mode == 1 ? nk_w : nq_w;
  int is_ref = t >= S;
  int tt = is_ref ? t - S : t;
  const float* xr = raw + (size_t)t * NQKV + mode * D;
  float v[8];
  float4 a = *(const float4*)(xr + tid * 8);
  float4 b = *(const float4*)(xr + tid * 8 + 4);
  v[0]=a.x; v[1]=a.y; v[2]=a.z; v[3]=a.w; v[4]=b.x; v[5]=b.y; v[6]=b.z; v[7]=b.w;
  int n = tid * 8;
  int head = n >> 7, d = n & 127;
  float o8[8];
  if (mode < 2) {
    float s = 0;
    #pragma unroll
    for (int i = 0; i < 8; i++) s += v[i] * v[i];
    float tot = blk_sum256(s, red, tid);
    float rinv = rsqrtf(tot * (1.0f / D) + 1e-6f);
    const float* cr = (is_ref ? cos_r : cos_h) + (size_t)tt * HD;
    const float* sr = (is_ref ? sin_r : sin_h) + (size_t)tt * HD;
    #pragma unroll
    for (int p = 0; p < 4; p++) {
      float x1 = v[2 * p] * rinv * nw[n + 2 * p];
      float x2 = v[2 * p + 1] * rinv * nw[n + 2 * p + 1];
      float ce = cr[d + 2 * p];
      float so = sr[d + 2 * p + 1];
      o8[2 * p]     = x1 * ce - x2 * so;
      o8[2 * p + 1] = x1 * so + x2 * ce;
    }
    if (mode == 0) {
      #pragma unroll
      for (int i = 0; i < 8; i++) o8[i] *= ATTN_SCALE;
    }
  } else {
    #pragma unroll
    for (int i = 0; i < 8; i++) o8[i] = v[i];
  }
  int f = tt / 576, rem = tt % 576;
  int row = rem / 24, col = rem - row * 24;
  int comb = row * 48 + col + (is_ref ? 24 : 0);
  size_t oidx = ((size_t)(f * NH + head) * CT + comb) * HD + d;
  us16 packed[8];
  #pragma unroll
  for (int i = 0; i < 8; i++) packed[i] = f2bf(o8[i]);
  *(uint4*)(out + oidx) = *(uint4*)packed;
}

// ---------- MFMA flash attention ----------
// grid: 64 fh * 18 q-tiles; block 256 (4 waves x 16 queries)
__global__ __launch_bounds__(256) void attn_mfma(
    const us16* __restrict__ qc, const us16* __restrict__ kc,
    const us16* __restrict__ vc, us16* __restrict__ ah, us16* __restrict__ ar) {
  __shared__ __align__(16) us16 Qs[64][136];     // stride 272B: frag-read 2-way banks
  __shared__ __align__(16) us16 Ks[64][136];
  __shared__ __align__(16) us16 Vts[128][72];    // transposed V: [d][key]
  __shared__ __align__(16) us16 Ps[4][16][72];   // per-wave P round-trip (C->A layout)
  int tid = threadIdx.x;
  int w = tid >> 6, l = tid & 63;
  int m = l & 15, quad = l >> 4;
  int bx = blockIdx.x;
  int fh = bx / 18, qt = bx % 18;
  size_t base = (size_t)fh * CT * HD;
  int qbase = qt * 64;

  // stage Q tile (64 x 128)
  {
    int row = tid >> 2, c0 = (tid & 3) * 32;
    const us16* src = qc + base + (size_t)(qbase + row) * HD + c0;
    #pragma unroll
    for (int j = 0; j < 4; j++)
      *(uint4*)&Qs[row][c0 + 8 * j] = *(const uint4*)(src + 8 * j);
  }
  __syncthreads();
  bf16x8 qf[4];
  #pragma unroll
  for (int c = 0; c < 4; c++)
    qf[c] = *(const bf16x8*)&Qs[16 * w + m][32 * c + quad * 8];

  float mo[4] = {-1e30f, -1e30f, -1e30f, -1e30f};
  float li[4] = {0.f, 0.f, 0.f, 0.f};
  f32x4 o[8] = {};

  #pragma unroll 1
  for (int kb = 0; kb < CT; kb += 64) {
    __syncthreads();
    {
      int row = tid >> 2, c0 = (tid & 3) * 32;
      const us16* src = kc + base + (size_t)(kb + row) * HD + c0;
      #pragma unroll
      for (int j = 0; j < 4; j++)
        *(uint4*)&Ks[row][c0 + 8 * j] = *(const uint4*)(src + 8 * j);
    }
    {
      int key = tid & 63, d0 = (tid >> 6) * 32;
      const us16* src = vc + base + (size_t)(kb + key) * HD + d0;
      #pragma unroll
      for (int j = 0; j < 4; j++) {
        uint4 vv = *(const uint4*)(src + 8 * j);
        us16 tmp[8];
        *(uint4*)tmp = vv;
        #pragma unroll
        for (int i = 0; i < 8; i++) Vts[d0 + 8 * j + i][key] = tmp[i];
      }
    }
    __syncthreads();
    f32x4 s[4] = {};
    #pragma unroll
    for (int kt = 0; kt < 4; kt++) {
      #pragma unroll
      for (int c = 0; c < 4; c++) {
        bf16x8 kf = *(const bf16x8*)&Ks[kt * 16 + m][32 * c + quad * 8];
        s[kt] = __builtin_amdgcn_mfma_f32_16x16x32_bf16(qf[c], kf, s[kt], 0, 0, 0);
      }
    }
    float al[4];
    #pragma unroll
    for (int r = 0; r < 4; r++) {
      float v = fmaxf(fmaxf(s[0][r], s[1][r]), fmaxf(s[2][r], s[3][r]));
      #pragma unroll
      for (int off = 8; off; off >>= 1) v = fmaxf(v, __shfl_xor(v, off));
      float mn = fmaxf(mo[r], v);
      al[r] = __expf(mo[r] - mn);
      mo[r] = mn;
      float ps = 0.f;
      #pragma unroll
      for (int kt = 0; kt < 4; kt++) {
        float p = __expf(s[kt][r] - mn);
        s[kt][r] = p;
        ps += p;
      }
      #pragma unroll
      for (int off = 8; off; off >>= 1) ps += __shfl_xor(ps, off);
      li[r] = li[r] * al[r] + ps;
    }
    #pragma unroll
    for (int kt = 0; kt < 4; kt++)
      #pragma unroll
      for (int r = 0; r < 4; r++)
        Ps[w][quad * 4 + r][kt * 16 + m] = f2bf(s[kt][r]);
    #pragma unroll
    for (int dt = 0; dt < 8; dt++)
      #pragma unroll
      for (int r = 0; r < 4; r++)
        o[dt][r] *= al[r];
    // barrier: Ps round-trip is cross-lane via LDS; s_barrier's lgkmcnt(0)
    // drain orders the us16 stores vs bf16x8 loads (TBAA won't).
    __syncthreads();
    #pragma unroll
    for (int c = 0; c < 2; c++) {
      bf16x8 pf = *(const bf16x8*)&Ps[w][m][32 * c + quad * 8];
      #pragma unroll
      for (int dt = 0; dt < 8; dt++) {
        bf16x8 vf = *(const bf16x8*)&Vts[dt * 16 + m][32 * c + quad * 8];
        o[dt] = __builtin_amdgcn_mfma_f32_16x16x32_bf16(pf, vf, o[dt], 0, 0, 0);
      }
    }
  }
  int f = fh >> 4, h = fh & 15;
  #pragma unroll
  for (int r = 0; r < 4; r++) {
    float rl = 1.0f / li[r];
    int q = qbase + 16 * w + quad * 4 + r;
    int row = q / 48, cc = q - row * 48;
    int isr = cc >= 24;
    int tok = f * 576 + row * 24 + (isr ? cc - 24 : cc);
    us16* dstp = (isr ? ar : ah) + (size_t)tok * D + h * HD;
    #pragma unroll
    for (int dt = 0; dt < 8; dt++)
      dstp[dt * 16 + m] = f2bf(o[dt][r] * rl);
  }
}

// ---------- out = x + gate[col] * attn ----------
__global__ __launch_bounds__(256) void residual_gate(
    const float* __restrict__ x, const float* __restrict__ attn,
    const float* __restrict__ gate, float* __restrict__ out) {
  size_t i = ((size_t)blockIdx.x * 256 + threadIdx.x) * 4;
  float4 xv = *(const float4*)(x + i);
  float4 av = *(const float4*)(attn + i);
  int n = (int)(i & (D - 1));
  float4 g = *(const float4*)(gate + n);
  float4 o;
  o.x = xv.x + g.x * av.x;
  o.y = xv.y + g.y * av.y;
  o.z = xv.z + g.z * av.z;
  o.w = xv.w + g.w * av.w;
  *(float4*)(out + i) = o;
}

// ---------- workspace layout (bytes) ----------
// Phase A (attention):
constexpr size_t O_WQ   = 0;          // bf16 DxD; wq|wk|wv contiguous = QKV BT
constexpr size_t O_WK   = 8388608;
constexpr size_t O_WV   = 16777216;
constexpr size_t O_WO   = 25165824;   // bf16 DxD
constexpr size_t O_NHR  = 33603584;   // bf16 [4608][2048] (h||r), ends 52477952
constexpr size_t O_RAW  = 52477952;   // fp32 [4608][6144] = 113.2MB, ends 165724160
constexpr size_t O_QC   = 165724160;  // bf16 combined per-head
constexpr size_t O_KC   = 184598528;
constexpr size_t O_VC   = 203472896;  // ends 222347264
constexpr size_t O_T1   = 222347264;  // fp32 6144
constexpr size_t O_T2   = 222371840;  // fp32 6144, ends 222396416
constexpr size_t O_AH   = O_RAW;                 // bf16 [4608][2048] (ah||ar)
constexpr size_t O_ATTN = O_RAW + 18874368;      // fp32 [4608][2048], ends 109101056
// Phase B (FFN) — overlays dead phase-A regions (stream-ordered):
constexpr size_t O_W1T  = 0;          // bf16 FFN*D = 33.5MB (over wq/wk/wv/wo)
constexpr size_t O_W2T  = 33554432;   // bf16 D*FFN (over nhr + dead raw head)
constexpr size_t O_N2   = 67108864;   // bf16 [4608][2048], ends 85983232
constexpr size_t O_MIDB = 85983232;   // bf16 [4608][8192] = 75.5MB, ends 161480704
constexpr size_t O_FOUT = 161480704;  // fp32 [4608][2048], ends 199229440

extern "C" void kernel_launch(void* const* d_in, const int* in_sizes, int n_in,
                              void* d_out, int out_size, void* d_ws, size_t ws_size,
                              hipStream_t stream) {
  (void)in_sizes; (void)n_in; (void)out_size; (void)ws_size;
  const float* hidden = (const float*)d_in[0];
  const float* refs   = (const float*)d_in[1];
  const float* temb   = (const float*)d_in[2];
  const float* cos_h  = (const float*)d_in[3];
  const float* sin_h  = (const float*)d_in[4];
  const float* cos_r  = (const float*)d_in[5];
  const float* sin_r  = (const float*)d_in[6];
  const float* ln1_lw = (const float*)d_in[7];
  const float* ln1_lb = (const float*)d_in[8];
  const float* ln1_nw = (const float*)d_in[9];
  const float* ln1_nb = (const float*)d_in[10];
  const float* ln2_lw = (const float*)d_in[11];
  const float* ln2_lb = (const float*)d_in[12];
  const float* ln2_nw = (const float*)d_in[13];
  const float* ln2_nb = (const float*)d_in[14];
  const float* wq = (const float*)d_in[15];
  const float* bq = (const float*)d_in[16];
  const float* wk = (const float*)d_in[17];
  const float* bk = (const float*)d_in[18];
  const float* wv = (const float*)d_in[19];
  const float* bv = (const float*)d_in[20];
  const float* nq_w = (const float*)d_in[21];
  const float* nk_w = (const float*)d_in[22];
  const float* wo = (const float*)d_in[23];
  const float* bo = (const float*)d_in[24];
  const float* ffn_w1 = (const float*)d_in[25];
  const float* ffn_b1 = (const float*)d_in[26];
  const float* ffn_w2 = (const float*)d_in[27];
  const float* ffn_b2 = (const float*)d_in[28];

  char* ws = (char*)d_ws;
  us16* p_wq  = (us16*)(ws + O_WQ);
  us16* p_wk  = (us16*)(ws + O_WK);
  us16* p_wv  = (us16*)(ws + O_WV);
  us16* p_wo  = (us16*)(ws + O_WO);
  us16* p_nhr = (us16*)(ws + O_NHR);
  float* p_raw = (float*)(ws + O_RAW);
  us16* p_qc  = (us16*)(ws + O_QC);
  us16* p_kc  = (us16*)(ws + O_KC);
  us16* p_vc  = (us16*)(ws + O_VC);
  float* p_t1 = (float*)(ws + O_T1);
  float* p_t2 = (float*)(ws + O_T2);
  us16* p_ah  = (us16*)(ws + O_AH);                 // h half
  us16* p_ar  = p_ah + (size_t)S * D;               // r half (contiguous)
  float* p_attn = (float*)(ws + O_ATTN);
  us16* p_w1t = (us16*)(ws + O_W1T);
  us16* p_w2t = (us16*)(ws + O_W2T);
  us16* p_n2  = (us16*)(ws + O_N2);
  us16* p_midb = (us16*)(ws + O_MIDB);
  float* p_fout = (float*)(ws + O_FOUT);
  float* outd = (float*)d_out;                      // [4608][2048] (h||r)

  // grids (all %8==0 for the bijective XCD swizzle)
  constexpr int G_QKV  = (NQKV / 256) * (S2 / 128);    // 24*36 = 864
  constexpr int G_WO   = (D / 128) * (S2 / 128);       // 16*36 = 576
  constexpr int G_FFN1 = (FFN / 256) * (S2 / 128);     // 32*36 = 1152
  constexpr int G_FFN2 = G_WO;                         // 576

  dim3 tb(32, 8);
  // --- phase A: attention ---
  transpose_cvt<<<dim3(64, 64), tb, 0, stream>>>(wq, p_wq, D, D);
  transpose_cvt<<<dim3(64, 64), tb, 0, stream>>>(wk, p_wk, D, D);
  transpose_cvt<<<dim3(64, 64), tb, 0, stream>>>(wv, p_wv, D, D);
  transpose_cvt<<<dim3(64, 64), tb, 0, stream>>>(wo, p_wo, D, D);
  temb_mod<<<48, 256, 0, stream>>>(temb, ln1_lw, ln1_lb, ln2_lw, ln2_lb, p_t1, p_t2);
  ln_mod<<<S, 256, 0, stream>>>(hidden, p_t1, ln1_nw, ln1_nb, p_nhr);
  ln_mod<<<S, 256, 0, stream>>>(refs,   p_t1, ln1_nw, ln1_nb, p_nhr + (size_t)S * D);
  // QKV mega-GEMM: [4608 x 6144] = nhr @ [wq|wk|wv]^T  (128x256 tiles)
  gemmW<0><<<G_QKV, 512, 0, stream>>>(p_nhr, p_wq, bq, bk, bv, D - 1,
                                      p_raw, S2, NQKV, D);
  qkv_scatter<<<3 * S2, 256, 0, stream>>>(p_raw, nq_w, nk_w,
                                          cos_h, sin_h, cos_r, sin_r,
                                          p_qc, p_kc, p_vc);
  attn_mfma<<<64 * 18, 256, 0, stream>>>(p_qc, p_kc, p_vc, p_ah, p_ar);
  // WO combined: [4608 x 2048] (R4-measured structure)
  gemm128<<<G_WO, 256, 0, stream>>>(p_ah, p_wo, bo, p_attn, S2, D, D);
  residual_gate<<<4608, 256, 0, stream>>>(hidden, p_attn, p_t1 + 2 * D, outd);
  residual_gate<<<4608, 256, 0, stream>>>(refs, p_attn + (size_t)S * D,
                                          p_t1 + 2 * D, outd + (size_t)S * D);
  // --- phase B: FFN (both streams batched) ---
  transpose_cvt<<<dim3(256, 64), tb, 0, stream>>>(ffn_w1, p_w1t, D, FFN);
  transpose_cvt<<<dim3(64, 256), tb, 0, stream>>>(ffn_w2, p_w2t, FFN, D);
  ln_mod<<<S2, 256, 0, stream>>>(outd, p_t2, ln2_nw, ln2_nb, p_n2);
  // FFN1 (gelu fused -> bf16), 128x256 tiles
  gemmW<1><<<G_FFN1, 512, 0, stream>>>(p_n2, p_w1t, ffn_b1, nullptr, nullptr,
                                       FFN - 1, p_midb, S2, FFN, D);
  // FFN2 (R4-measured structure) then fused-free residual
  gemm128<<<G_FFN2, 256, 0, stream>>>(p_midb, p_w2t, ffn_b2, p_fout, S2, D, FFN);
  residual_gate<<<9216, 256, 0, stream>>>(outd, p_fout, p_t2 + 2 * D, outd);
}